// Round 1
// baseline (173.559 us; speedup 1.0000x reference)
//
#include <hip/hip_runtime.h>
#include <hip/hip_bf16.h>

#define NN 4096
#define SDIM 64
#define HID 128
#define HEADS 4
#define FF 32
#define NSPLIT 16

// ---------------- workspace layout (floats) ----------------
// hbuf  : 0        .. 524288      h[hd][m][f]  (4*4096*32)
// s1    : 524288   (4*4096)
// s2    : 540672
// E2    : 557056
// E2s   : 573440
// cpos  : 589824
// cneg  : 606208
// thr   : 622592
// pout  : 638976   (16*4*4096*32 = 8388608)
// pden  : 9027584  (16*4*4096   = 262144)
// feat  : 9289728  (4096*128    = 524288)
// total : 9814016 floats = 39.3 MB

// ============ K1: fused state->x1->x2->h, s1, s2 ============
// 128 threads, 8 rows per block, 512 blocks
__global__ void k_prep(const float* __restrict__ state,
                       const float* __restrict__ W1, const float* __restrict__ b1,
                       const float* __restrict__ W2, const float* __restrict__ b2,
                       const float* __restrict__ Wg, const float* __restrict__ ag,
                       float* __restrict__ hbuf, float* __restrict__ s1b, float* __restrict__ s2b) {
    __shared__ float srow[8][64];
    __shared__ float x1s[8][128];
    __shared__ float x2s[8][128];
    int tid = threadIdx.x;
    int r0 = blockIdx.x * 8;

    // stage 8 state rows (512 floats = 128 float4)
    ((float4*)&srow[0][0])[tid] = ((const float4*)(state + (size_t)r0 * SDIM))[tid];
    __syncthreads();

    // x1 = relu(state@W1+b1)
    float acc[8];
    {
        float bb = b1[tid];
#pragma unroll
        for (int r = 0; r < 8; r++) acc[r] = bb;
        for (int k = 0; k < SDIM; k++) {
            float w = W1[k * HID + tid];
#pragma unroll
            for (int r = 0; r < 8; r++) acc[r] += w * srow[r][k];
        }
#pragma unroll
        for (int r = 0; r < 8; r++) x1s[r][tid] = fmaxf(acc[r], 0.f);
    }
    __syncthreads();

    // x2 = relu(x1@W2+b2)
    {
        float bb = b2[tid];
#pragma unroll
        for (int r = 0; r < 8; r++) acc[r] = bb;
        for (int k = 0; k < HID; k++) {
            float w = W2[k * HID + tid];
#pragma unroll
            for (int r = 0; r < 8; r++) acc[r] += w * x1s[r][k];
        }
#pragma unroll
        for (int r = 0; r < 8; r++) x2s[r][tid] = fmaxf(acc[r], 0.f);
    }
    __syncthreads();

    // h[hd][n][f] = sum_k x2[n][k]*Wg[hd][k][f];   s1 = h.a1, s2 = h.a2
    int hd = tid >> 5, f = tid & 31;
    float hacc[8];
#pragma unroll
    for (int r = 0; r < 8; r++) hacc[r] = 0.f;
    for (int k = 0; k < HID; k++) {
        float w = Wg[hd * (HID * FF) + k * FF + f];
#pragma unroll
        for (int r = 0; r < 8; r++) hacc[r] += w * x2s[r][k];
    }
    float a1v = ag[hd * 64 + f];
    float a2v = ag[hd * 64 + 32 + f];
#pragma unroll
    for (int r = 0; r < 8; r++) {
        hbuf[(size_t)hd * (NN * FF) + (size_t)(r0 + r) * FF + f] = hacc[r];
        float p1 = hacc[r] * a1v;
        float p2 = hacc[r] * a2v;
#pragma unroll
        for (int s = 16; s >= 1; s >>= 1) {
            p1 += __shfl_xor(p1, s, 32);
            p2 += __shfl_xor(p2, s, 32);
        }
        if (f == 0) {
            s1b[hd * NN + r0 + r] = p1;
            s2b[hd * NN + r0 + r] = p2;
        }
    }
}

// ============ K2: per-head A2 + E2/E2s/cpos/cneg/thr ============
__global__ void k_headprep(const float* __restrict__ s1b, const float* __restrict__ s2b,
                           float* __restrict__ E2, float* __restrict__ E2s,
                           float* __restrict__ cpos, float* __restrict__ cneg,
                           float* __restrict__ thr) {
    int hd = blockIdx.x;
    int tid = threadIdx.x;
    __shared__ float red[256];
    float m = -1e30f;
    for (int i = tid; i < NN; i += 256) m = fmaxf(m, s2b[hd * NN + i]);
    red[tid] = m;
    __syncthreads();
    for (int s = 128; s > 0; s >>= 1) {
        if (tid < s) red[tid] = fmaxf(red[tid], red[tid + s]);
        __syncthreads();
    }
    float A2 = red[0];
    for (int i = tid; i < NN; i += 256) {
        int idx = hd * NN + i;
        float v2 = s2b[idx];
        E2[idx]  = __expf(v2 - A2);
        E2s[idx] = __expf(0.2f * (v2 - A2));
        float v1 = s1b[idx];
        float u = v1 + A2;
        float C = (u >= 0.f) ? u : 0.2f * u;   // C[n] = lrelu(s1+A2) >= row max of lrelu scores
        cpos[idx] = __expf(u - C);
        cneg[idx] = __expf(0.2f * u - C);
        thr[idx] = -v1;
    }
}

// ============ K3: attention (the big one) ============
// block: 256 thr = 4 waves (wave=head), lane = row-in-tile (64 rows)
// grid: 64 row-tiles * NSPLIT m-chunks
__global__ __launch_bounds__(256) void k_attn(
        const float* __restrict__ hbuf, const int* __restrict__ adj,
        const float* __restrict__ s2b, const float* __restrict__ E2,
        const float* __restrict__ E2s, const float* __restrict__ cposb,
        const float* __restrict__ cnegb, const float* __restrict__ thrb,
        float* __restrict__ pout, float* __restrict__ pden) {
    __shared__ float4 h4[4 * 64 * 8];    // 32 KB  h[hd][mm][f/4]
    __shared__ float4 scal[4 * 64];      // 4 KB   (s2, E2, E2s, -)
    __shared__ float adjt[64 * 65];      // 16.6 KB, padded stride 65

    int tid = threadIdx.x;
    int tile = blockIdx.x & 63;
    int split = blockIdx.x >> 6;
    int n0 = tile * 64;
    int hd = tid >> 6, lane = tid & 63;
    int n = n0 + lane;

    float thr_r = thrb[hd * NN + n];
    float cp = cposb[hd * NN + n];
    float cn = cnegb[hd * NN + n];

    float acc[32];
#pragma unroll
    for (int i = 0; i < 32; i++) acc[i] = 0.f;
    float den = 0.f;

    for (int t = 0; t < 4; t++) {
        int m0 = split * (NN / NSPLIT) + t * 64;
        // stage h tile: 2048 float4
#pragma unroll
        for (int it = 0; it < 8; it++) {
            int li = tid + it * 256;
            int hd2 = li >> 9;
            int rem = li & 511;
            int mm = rem >> 3, fq = rem & 7;
            h4[li] = *(const float4*)(hbuf + (size_t)hd2 * (NN * FF) + (size_t)(m0 + mm) * FF + fq * 4);
        }
        // stage per-m scalars
        {
            int hd2 = tid >> 6, mm = tid & 63;
            int idx = hd2 * NN + m0 + mm;
            scal[tid] = make_float4(s2b[idx], E2[idx], E2s[idx], 0.f);
        }
        // stage adjacency tile as float, padded
#pragma unroll
        for (int it = 0; it < 4; it++) {
            int li = tid + it * 256;
            int r = li >> 4, c4 = li & 15;
            int4 a = *(const int4*)(adj + (size_t)(n0 + r) * NN + m0 + c4 * 4);
            float* dst = &adjt[r * 65 + c4 * 4];
            dst[0] = (float)a.x; dst[1] = (float)a.y; dst[2] = (float)a.z; dst[3] = (float)a.w;
        }
        __syncthreads();

        const float4* hrow = &h4[hd * 512];
        const float4* srow = &scal[hd * 64];
        for (int mm = 0; mm < 64; mm++) {
            float4 sc = srow[mm];
            float adjf = adjt[lane * 65 + mm];
            bool sel = (sc.x >= thr_r);
            float w = (sel ? cp : cn) * (sel ? sc.y : sc.z) * adjf;
            den += w;
            const float4* hp = hrow + mm * 8;
#pragma unroll
            for (int fq = 0; fq < 8; fq++) {
                float4 hv = hp[fq];
                acc[fq * 4 + 0] += w * hv.x;
                acc[fq * 4 + 1] += w * hv.y;
                acc[fq * 4 + 2] += w * hv.z;
                acc[fq * 4 + 3] += w * hv.w;
            }
        }
        __syncthreads();
    }

    float* po = pout + ((size_t)(split * 4 + hd) * NN + n) * FF;
#pragma unroll
    for (int fq = 0; fq < 8; fq++)
        ((float4*)po)[fq] = make_float4(acc[fq * 4], acc[fq * 4 + 1], acc[fq * 4 + 2], acc[fq * 4 + 3]);
    pden[(split * 4 + hd) * NN + n] = den;
}

// ============ K4: reduce partials -> feat (n, hd*32+f) ============
__global__ void k_reduce(const float* __restrict__ pout, const float* __restrict__ pden,
                         float* __restrict__ feat) {
    int gid = blockIdx.x * 256 + threadIdx.x;   // 4*4096*32 total
    int f = gid & 31;
    int n = (gid >> 5) & (NN - 1);
    int hd = gid >> 17;
    float den = 0.f;
#pragma unroll
    for (int s = 0; s < NSPLIT; s++) den += pden[(s * 4 + hd) * NN + n];
    float o = 0.f;
#pragma unroll
    for (int s = 0; s < NSPLIT; s++) o += pout[((size_t)(s * 4 + hd) * NN + n) * FF + f];
    feat[(size_t)n * HID + hd * FF + f] = o / fmaxf(den, 1e-30f);
}

// ============ K5: policy head ============
__global__ void k_policy(const float* __restrict__ feat,
                         const float* __restrict__ Wp1, const float* __restrict__ bp1,
                         const float* __restrict__ Wp2, const float* __restrict__ bp2,
                         float* __restrict__ out) {
    __shared__ float fr[8][128];
    __shared__ float ph[8][128];
    int tid = threadIdx.x;
    int r0 = blockIdx.x * 8;
    const float4* fp = (const float4*)(feat + (size_t)r0 * HID);
    ((float4*)&fr[0][0])[tid] = fp[tid];
    ((float4*)&fr[0][0])[tid + 128] = fp[tid + 128];
    __syncthreads();
    float acc[8];
    float bb = bp1[tid];
#pragma unroll
    for (int r = 0; r < 8; r++) acc[r] = bb;
    for (int k = 0; k < HID; k++) {
        float w = Wp1[k * HID + tid];
#pragma unroll
        for (int r = 0; r < 8; r++) acc[r] += w * fr[r][k];
    }
#pragma unroll
    for (int r = 0; r < 8; r++) ph[r][tid] = fmaxf(acc[r], 0.f);
    __syncthreads();
    int c = tid & 31;
    float b2v = bp2[c];
#pragma unroll
    for (int pass = 0; pass < 2; pass++) {
        int r = (tid >> 5) + pass * 4;
        float lacc = b2v;
        for (int k = 0; k < HID; k++) lacc += ph[r][k] * Wp2[k * 32 + c];
        float mx = lacc;
#pragma unroll
        for (int s = 16; s >= 1; s >>= 1) mx = fmaxf(mx, __shfl_xor(mx, s, 32));
        float e = __expf(lacc - mx);
        float sm = e;
#pragma unroll
        for (int s = 16; s >= 1; s >>= 1) sm += __shfl_xor(sm, s, 32);
        out[(size_t)(r0 + r) * 32 + c] = e / sm;
    }
}

// ============ K6: value head ============
__global__ void k_value(const float* __restrict__ feat,
                        const float* __restrict__ Wv1, const float* __restrict__ bv1,
                        const float* __restrict__ Wv2, const float* __restrict__ bv2,
                        float* __restrict__ out) {
    __shared__ float fr[8][128];
    __shared__ float vh[8][128];
    __shared__ float red[2][8];
    int tid = threadIdx.x;
    int r0 = blockIdx.x * 8;
    const float4* fp = (const float4*)(feat + (size_t)r0 * HID);
    ((float4*)&fr[0][0])[tid] = fp[tid];
    ((float4*)&fr[0][0])[tid + 128] = fp[tid + 128];
    __syncthreads();
    float acc[8];
    float bb = bv1[tid];
#pragma unroll
    for (int r = 0; r < 8; r++) acc[r] = bb;
    for (int k = 0; k < HID; k++) {
        float w = Wv1[k * HID + tid];
#pragma unroll
        for (int r = 0; r < 8; r++) acc[r] += w * fr[r][k];
    }
#pragma unroll
    for (int r = 0; r < 8; r++) vh[r][tid] = fmaxf(acc[r], 0.f);
    __syncthreads();
    float wv = Wv2[tid];
    int wave = tid >> 6, lane = tid & 63;
#pragma unroll
    for (int r = 0; r < 8; r++) {
        float p = vh[r][tid] * wv;
#pragma unroll
        for (int s = 32; s >= 1; s >>= 1) p += __shfl_xor(p, s, 64);
        if (lane == 0) red[wave][r] = p;
    }
    __syncthreads();
    if (tid < 8) out[131072 + r0 + tid] = red[0][tid] + red[1][tid] + bv2[0];
}

extern "C" void kernel_launch(void* const* d_in, const int* in_sizes, int n_in,
                              void* d_out, int out_size, void* d_ws, size_t ws_size,
                              hipStream_t stream) {
    const float* state = (const float*)d_in[0];
    const int*   adj   = (const int*)d_in[1];
    const float* W1  = (const float*)d_in[2];
    const float* b1  = (const float*)d_in[3];
    const float* W2  = (const float*)d_in[4];
    const float* b2  = (const float*)d_in[5];
    const float* Wg  = (const float*)d_in[6];
    const float* ag  = (const float*)d_in[7];
    const float* Wp1 = (const float*)d_in[8];
    const float* bp1 = (const float*)d_in[9];
    const float* Wp2 = (const float*)d_in[10];
    const float* bp2 = (const float*)d_in[11];
    const float* Wv1 = (const float*)d_in[12];
    const float* bv1 = (const float*)d_in[13];
    const float* Wv2 = (const float*)d_in[14];
    const float* bv2 = (const float*)d_in[15];
    float* out = (float*)d_out;
    float* ws = (float*)d_ws;

    float* hbuf = ws;
    float* s1b  = ws + 524288;
    float* s2b  = ws + 540672;
    float* E2   = ws + 557056;
    float* E2s  = ws + 573440;
    float* cpos = ws + 589824;
    float* cneg = ws + 606208;
    float* thr  = ws + 622592;
    float* pout = ws + 638976;
    float* pden = ws + 9027584;
    float* feat = ws + 9289728;

    hipLaunchKernelGGL(k_prep, dim3(NN / 8), dim3(128), 0, stream,
                       state, W1, b1, W2, b2, Wg, ag, hbuf, s1b, s2b);
    hipLaunchKernelGGL(k_headprep, dim3(HEADS), dim3(256), 0, stream,
                       s1b, s2b, E2, E2s, cpos, cneg, thr);
    hipLaunchKernelGGL(k_attn, dim3(64 * NSPLIT), dim3(256), 0, stream,
                       hbuf, adj, s2b, E2, E2s, cpos, cneg, thr, pout, pden);
    hipLaunchKernelGGL(k_reduce, dim3((HEADS * NN * FF) / 256), dim3(256), 0, stream,
                       pout, pden, feat);
    hipLaunchKernelGGL(k_policy, dim3(NN / 8), dim3(128), 0, stream,
                       feat, Wp1, bp1, Wp2, bp2, out);
    hipLaunchKernelGGL(k_value, dim3(NN / 8), dim3(128), 0, stream,
                       feat, Wv1, bv1, Wv2, bv2, out);
}

// Round 2
// 116.146 us; speedup vs baseline: 1.4943x; 1.4943x over previous
//
#include <hip/hip_runtime.h>
#include <hip/hip_bf16.h>

#define NN 4096
#define SDIM 64
#define HID 128
#define HEADS 4
#define FF 32
#define NSPLIT 16

typedef __attribute__((ext_vector_type(8))) short bfrag;      // 8 bf16 = 4 VGPR (MFMA A/B)
typedef __attribute__((ext_vector_type(4))) float f32x4;      // MFMA C/D
typedef __attribute__((ext_vector_type(8))) float f32x8;
typedef __attribute__((ext_vector_type(8))) unsigned short us8;

__device__ inline short bfbits(float x) {
    __hip_bfloat16 h = __float2bfloat16(x);
    short s; __builtin_memcpy(&s, &h, 2); return s;
}

// ---------------- workspace layout (float units) ----------------
// hTf  : 0        (262144 f = 524288 bf16)  fragment-ordered h^T
// s1   : 262144   (16384)
// s2   : 278528
// E2   : 294912
// E2s  : 311296
// cpos : 327680
// cneg : 344064
// thr  : 360448
// abit : 376832   (524288 f = 2 MB bits)   -- overlapped with feat (abit dead
// feat : 376832   (524288)                    before k_reduce writes feat)
// pout : 901120   (8388608)
// pden : 9289728  (262144)
// total 9551872 floats = 38.2 MB (< R0's 39.3 MB, known to fit)

// ============ K1: fused state->x1->x2->h^T(bf16 frag layout), s1, s2 ============
__global__ void k_prep(const float* __restrict__ state,
                       const float* __restrict__ W1, const float* __restrict__ b1,
                       const float* __restrict__ W2, const float* __restrict__ b2,
                       const float* __restrict__ Wg, const float* __restrict__ ag,
                       unsigned short* __restrict__ hTf,
                       float* __restrict__ s1b, float* __restrict__ s2b) {
    __shared__ float srow[8][64];
    __shared__ float x1s[8][128];
    __shared__ float x2s[8][128];
    int tid = threadIdx.x;
    int r0 = blockIdx.x * 8;

    ((float4*)&srow[0][0])[tid] = ((const float4*)(state + (size_t)r0 * SDIM))[tid];
    __syncthreads();

    float acc[8];
    {
        float bb = b1[tid];
#pragma unroll
        for (int r = 0; r < 8; r++) acc[r] = bb;
        for (int k = 0; k < SDIM; k++) {
            float w = W1[k * HID + tid];
#pragma unroll
            for (int r = 0; r < 8; r++) acc[r] += w * srow[r][k];
        }
#pragma unroll
        for (int r = 0; r < 8; r++) x1s[r][tid] = fmaxf(acc[r], 0.f);
    }
    __syncthreads();
    {
        float bb = b2[tid];
#pragma unroll
        for (int r = 0; r < 8; r++) acc[r] = bb;
        for (int k = 0; k < HID; k++) {
            float w = W2[k * HID + tid];
#pragma unroll
            for (int r = 0; r < 8; r++) acc[r] += w * x1s[r][k];
        }
#pragma unroll
        for (int r = 0; r < 8; r++) x2s[r][tid] = fmaxf(acc[r], 0.f);
    }
    __syncthreads();

    int hd = tid >> 5, f = tid & 31;
    float hacc[8];
#pragma unroll
    for (int r = 0; r < 8; r++) hacc[r] = 0.f;
    for (int k = 0; k < HID; k++) {
        float w = Wg[hd * (HID * FF) + k * FF + f];
#pragma unroll
        for (int r = 0; r < 8; r++) hacc[r] += w * x2s[r][k];
    }

    // h^T in MFMA-fragment order: idx(hd,f,m) =
    //   ((hd*128 + (m>>5))*2 + (f>>4))*512 + (f&15)*32 + ((m&31)>>3)*8 + (m&7)
    {
        int bn = f >> 4, fr = f & 15;
        int mb = r0 >> 5, mo = (r0 & 31) >> 3;
        us8 pk;
#pragma unroll
        for (int r = 0; r < 8; r++) pk[r] = (unsigned short)bfbits(hacc[r]);
        *(us8*)(hTf + (size_t)((hd * 128 + mb) * 2 + bn) * 512 + fr * 32 + mo * 8) = pk;
    }

    float a1v = ag[hd * 64 + f];
    float a2v = ag[hd * 64 + 32 + f];
#pragma unroll
    for (int r = 0; r < 8; r++) {
        float p1 = hacc[r] * a1v;
        float p2 = hacc[r] * a2v;
#pragma unroll
        for (int s = 16; s >= 1; s >>= 1) {
            p1 += __shfl_xor(p1, s, 32);
            p2 += __shfl_xor(p2, s, 32);
        }
        if (f == 0) {
            s1b[hd * NN + r0 + r] = p1;
            s2b[hd * NN + r0 + r] = p2;
        }
    }
}

// ============ K2: per-head A2 + E2/E2s/cpos/cneg/thr ============
__global__ void k_headprep(const float* __restrict__ s1b, const float* __restrict__ s2b,
                           float* __restrict__ E2, float* __restrict__ E2s,
                           float* __restrict__ cpos, float* __restrict__ cneg,
                           float* __restrict__ thr) {
    int hd = blockIdx.x;
    int tid = threadIdx.x;
    __shared__ float red[256];
    float m = -1e30f;
    for (int i = tid; i < NN; i += 256) m = fmaxf(m, s2b[hd * NN + i]);
    red[tid] = m;
    __syncthreads();
    for (int s = 128; s > 0; s >>= 1) {
        if (tid < s) red[tid] = fmaxf(red[tid], red[tid + s]);
        __syncthreads();
    }
    float A2 = red[0];
    for (int i = tid; i < NN; i += 256) {
        int idx = hd * NN + i;
        float v2 = s2b[idx];
        E2[idx]  = __expf(v2 - A2);
        E2s[idx] = __expf(0.2f * (v2 - A2));
        float v1 = s1b[idx];
        float u = v1 + A2;
        float C = (u >= 0.f) ? u : 0.2f * u;
        cpos[idx] = __expf(u - C);
        cneg[idx] = __expf(0.2f * u - C);
        thr[idx] = -v1;
    }
}

// ============ K2b: pack adjacency to bitmask (the only 64 MB read) ============
// grid 4096 (one row/block), 256 threads; thread t packs ints m=t*16..t*16+15
__global__ void k_pack(const int* __restrict__ adj, unsigned int* __restrict__ abit) {
    int r = blockIdx.x, t = threadIdx.x;
    const int4* ap = (const int4*)(adj + (size_t)r * NN + t * 16);
    unsigned int b = 0;
#pragma unroll
    for (int i = 0; i < 4; i++) {
        int4 a = ap[i];
        b |= (unsigned int)(a.x != 0) << (i * 4 + 0);
        b |= (unsigned int)(a.y != 0) << (i * 4 + 1);
        b |= (unsigned int)(a.z != 0) << (i * 4 + 2);
        b |= (unsigned int)(a.w != 0) << (i * 4 + 3);
    }
    ((unsigned short*)abit)[r * 256 + t] = (unsigned short)b;
}

// ============ K3: attention — w built on the fly, MFMA contraction ============
// block: 256 thr = 4 waves (wave = head); per block: 64 n-rows x 256 m-chunk.
// grid: 64 row-tiles * NSPLIT
__global__ __launch_bounds__(256) void k_attn(
        const unsigned int* __restrict__ abit, const unsigned short* __restrict__ hTf,
        const float* __restrict__ s2b, const float* __restrict__ E2,
        const float* __restrict__ E2s, const float* __restrict__ cposb,
        const float* __restrict__ cnegb, const float* __restrict__ thrb,
        float* __restrict__ pout, float* __restrict__ pden) {
    __shared__ unsigned int abits[64][9];   // 256-bit rows, padded stride 9

    int tid = threadIdx.x;
    int tile = blockIdx.x & 63;
    int split = blockIdx.x >> 6;
    int n0 = tile * 64, m0 = split * 256;

    {   // stage bitmask chunk: 64 rows x 8 words
        int r = tid >> 2, q = tid & 3;
        const unsigned int* src = abit + (size_t)(n0 + r) * 128 + split * 8 + q * 2;
        abits[r][q * 2 + 0] = src[0];
        abits[r][q * 2 + 1] = src[1];
    }
    __syncthreads();

    int hd = tid >> 6, lane = tid & 63;
    int fr = lane & 15, mo = lane >> 4;

    float thrv[4], cpv[4], cnv[4];
#pragma unroll
    for (int am = 0; am < 4; am++) {
        int n = n0 + am * 16 + fr;
        thrv[am] = thrb[hd * NN + n];
        cpv[am] = cposb[hd * NN + n];
        cnv[am] = cnegb[hd * NN + n];
    }

    f32x4 acc[4][2];
#pragma unroll
    for (int am = 0; am < 4; am++)
#pragma unroll
        for (int bn = 0; bn < 2; bn++) acc[am][bn] = (f32x4){0.f, 0.f, 0.f, 0.f};
    float den[4] = {0.f, 0.f, 0.f, 0.f};

    const float* s2p = s2b + hd * NN + m0;
    const float* e2p = E2 + hd * NN + m0;
    const float* esp = E2s + hd * NN + m0;
    const unsigned short* hbase = hTf + (size_t)((hd * 128 + (m0 >> 5)) * 2) * 512 + fr * 32 + mo * 8;

#pragma unroll 2
    for (int ks = 0; ks < 8; ks++) {
        int mb = ks * 32 + mo * 8;                 // lane's 8-m base within chunk
        f32x8 s2v = *(const f32x8*)(s2p + mb);
        f32x8 e2v = *(const f32x8*)(e2p + mb);
        f32x8 esv = *(const f32x8*)(esp + mb);
        bfrag B0 = *(const bfrag*)(hbase + ks * 1024);
        bfrag B1 = *(const bfrag*)(hbase + ks * 1024 + 512);

#pragma unroll
        for (int am = 0; am < 4; am++) {
            unsigned int bits = abits[am * 16 + fr][ks] >> (mo * 8);
            bfrag a8;
            float dsum = 0.f;
#pragma unroll
            for (int j = 0; j < 8; j++) {
                bool sel = s2v[j] >= thrv[am];
                float c = sel ? cpv[am] : cnv[am];
                float e = sel ? e2v[j] : esv[j];
                float wv = c * e;
                wv = ((bits >> j) & 1u) ? wv : 0.f;
                dsum += wv;
                a8[j] = bfbits(wv);
            }
            den[am] += dsum;
            acc[am][0] = __builtin_amdgcn_mfma_f32_16x16x32_bf16(a8, B0, acc[am][0], 0, 0, 0);
            acc[am][1] = __builtin_amdgcn_mfma_f32_16x16x32_bf16(a8, B1, acc[am][1], 0, 0, 0);
        }
    }

    // den reduce across the 4 k-lane-groups (lanes differing in bits 4..5)
#pragma unroll
    for (int am = 0; am < 4; am++) {
        den[am] += __shfl_xor(den[am], 16);
        den[am] += __shfl_xor(den[am], 32);
    }

    float* pob = pout + ((size_t)(split * 4 + hd) * NN + n0) * FF;
#pragma unroll
    for (int am = 0; am < 4; am++) {
#pragma unroll
        for (int bn = 0; bn < 2; bn++) {
            f32x4 c = acc[am][bn];
#pragma unroll
            for (int r = 0; r < 4; r++)
                pob[(am * 16 + mo * 4 + r) * FF + bn * 16 + fr] = c[r];
        }
        if (mo == 0)
            pden[(size_t)(split * 4 + hd) * NN + n0 + am * 16 + fr] = den[am];
    }
}

// ============ K4: reduce partials -> feat (n, hd*32+f) ============
__global__ void k_reduce(const float* __restrict__ pout, const float* __restrict__ pden,
                         float* __restrict__ feat) {
    int gid = blockIdx.x * 256 + threadIdx.x;
    int f = gid & 31;
    int n = (gid >> 5) & (NN - 1);
    int hd = gid >> 17;
    float den = 0.f;
#pragma unroll
    for (int s = 0; s < NSPLIT; s++) den += pden[(size_t)(s * 4 + hd) * NN + n];
    float o = 0.f;
#pragma unroll
    for (int s = 0; s < NSPLIT; s++) o += pout[((size_t)(s * 4 + hd) * NN + n) * FF + f];
    feat[(size_t)n * HID + hd * FF + f] = o / fmaxf(den, 1e-30f);
}

// ============ K5: policy head ============
__global__ void k_policy(const float* __restrict__ feat,
                         const float* __restrict__ Wp1, const float* __restrict__ bp1,
                         const float* __restrict__ Wp2, const float* __restrict__ bp2,
                         float* __restrict__ out) {
    __shared__ float fr[8][128];
    __shared__ float ph[8][128];
    int tid = threadIdx.x;
    int r0 = blockIdx.x * 8;
    const float4* fp = (const float4*)(feat + (size_t)r0 * HID);
    ((float4*)&fr[0][0])[tid] = fp[tid];
    ((float4*)&fr[0][0])[tid + 128] = fp[tid + 128];
    __syncthreads();
    float acc[8];
    float bb = bp1[tid];
#pragma unroll
    for (int r = 0; r < 8; r++) acc[r] = bb;
    for (int k = 0; k < HID; k++) {
        float w = Wp1[k * HID + tid];
#pragma unroll
        for (int r = 0; r < 8; r++) acc[r] += w * fr[r][k];
    }
#pragma unroll
    for (int r = 0; r < 8; r++) ph[r][tid] = fmaxf(acc[r], 0.f);
    __syncthreads();
    int c = tid & 31;
    float b2v = bp2[c];
#pragma unroll
    for (int pass = 0; pass < 2; pass++) {
        int r = (tid >> 5) + pass * 4;
        float lacc = b2v;
        for (int k = 0; k < HID; k++) lacc += ph[r][k] * Wp2[k * 32 + c];
        float mx = lacc;
#pragma unroll
        for (int s = 16; s >= 1; s >>= 1) mx = fmaxf(mx, __shfl_xor(mx, s, 32));
        float e = __expf(lacc - mx);
        float sm = e;
#pragma unroll
        for (int s = 16; s >= 1; s >>= 1) sm += __shfl_xor(sm, s, 32);
        out[(size_t)(r0 + r) * 32 + c] = e / sm;
    }
}

// ============ K6: value head ============
__global__ void k_value(const float* __restrict__ feat,
                        const float* __restrict__ Wv1, const float* __restrict__ bv1,
                        const float* __restrict__ Wv2, const float* __restrict__ bv2,
                        float* __restrict__ out) {
    __shared__ float fr[8][128];
    __shared__ float vh[8][128];
    __shared__ float red[2][8];
    int tid = threadIdx.x;
    int r0 = blockIdx.x * 8;
    const float4* fp = (const float4*)(feat + (size_t)r0 * HID);
    ((float4*)&fr[0][0])[tid] = fp[tid];
    ((float4*)&fr[0][0])[tid + 128] = fp[tid + 128];
    __syncthreads();
    float acc[8];
    float bb = bv1[tid];
#pragma unroll
    for (int r = 0; r < 8; r++) acc[r] = bb;
    for (int k = 0; k < HID; k++) {
        float w = Wv1[k * HID + tid];
#pragma unroll
        for (int r = 0; r < 8; r++) acc[r] += w * fr[r][k];
    }
#pragma unroll
    for (int r = 0; r < 8; r++) vh[r][tid] = fmaxf(acc[r], 0.f);
    __syncthreads();
    float wv = Wv2[tid];
    int wave = tid >> 6, lane = tid & 63;
#pragma unroll
    for (int r = 0; r < 8; r++) {
        float p = vh[r][tid] * wv;
#pragma unroll
        for (int s = 32; s >= 1; s >>= 1) p += __shfl_xor(p, s, 64);
        if (lane == 0) red[wave][r] = p;
    }
    __syncthreads();
    if (tid < 8) out[131072 + r0 + tid] = red[0][tid] + red[1][tid] + bv2[0];
}

extern "C" void kernel_launch(void* const* d_in, const int* in_sizes, int n_in,
                              void* d_out, int out_size, void* d_ws, size_t ws_size,
                              hipStream_t stream) {
    const float* state = (const float*)d_in[0];
    const int*   adj   = (const int*)d_in[1];
    const float* W1  = (const float*)d_in[2];
    const float* b1  = (const float*)d_in[3];
    const float* W2  = (const float*)d_in[4];
    const float* b2  = (const float*)d_in[5];
    const float* Wg  = (const float*)d_in[6];
    const float* ag  = (const float*)d_in[7];
    const float* Wp1 = (const float*)d_in[8];
    const float* bp1 = (const float*)d_in[9];
    const float* Wp2 = (const float*)d_in[10];
    const float* bp2 = (const float*)d_in[11];
    const float* Wv1 = (const float*)d_in[12];
    const float* bv1 = (const float*)d_in[13];
    const float* Wv2 = (const float*)d_in[14];
    const float* bv2 = (const float*)d_in[15];
    float* out = (float*)d_out;
    float* ws = (float*)d_ws;

    unsigned short* hTf = (unsigned short*)ws;          // 524288 bf16
    float* s1b  = ws + 262144;
    float* s2b  = ws + 278528;
    float* E2   = ws + 294912;
    float* E2s  = ws + 311296;
    float* cpos = ws + 327680;
    float* cneg = ws + 344064;
    float* thr  = ws + 360448;
    unsigned int* abit = (unsigned int*)(ws + 376832);  // 2 MB
    float* feat = ws + 376832;                          // overlaps abit (abit dead by then)
    float* pout = ws + 901120;
    float* pden = ws + 9289728;

    hipLaunchKernelGGL(k_pack, dim3(NN), dim3(256), 0, stream, adj, abit);
    hipLaunchKernelGGL(k_prep, dim3(NN / 8), dim3(128), 0, stream,
                       state, W1, b1, W2, b2, Wg, ag, hTf, s1b, s2b);
    hipLaunchKernelGGL(k_headprep, dim3(HEADS), dim3(256), 0, stream,
                       s1b, s2b, E2, E2s, cpos, cneg, thr);
    hipLaunchKernelGGL(k_attn, dim3(64 * NSPLIT), dim3(256), 0, stream,
                       abit, hTf, s2b, E2, E2s, cpos, cneg, thr, pout, pden);
    hipLaunchKernelGGL(k_reduce, dim3((HEADS * NN * FF) / 256), dim3(256), 0, stream,
                       pout, pden, feat);
    hipLaunchKernelGGL(k_policy, dim3(NN / 8), dim3(128), 0, stream,
                       feat, Wp1, bp1, Wp2, bp2, out);
    hipLaunchKernelGGL(k_value, dim3(NN / 8), dim3(128), 0, stream,
                       feat, Wv1, bv1, Wv2, bv2, out);
}

// Round 4
// 89.015 us; speedup vs baseline: 1.9498x; 1.3048x over previous
//
#include <hip/hip_runtime.h>
#include <hip/hip_bf16.h>

#define NN 4096
#define SDIM 64
#define HID 128
#define HEADS 4
#define FF 32
#define NSPLIT 8

typedef __attribute__((ext_vector_type(8))) short bfrag;      // 8 bf16 = 4 VGPR (MFMA A/B)
typedef __attribute__((ext_vector_type(4))) float f32x4;      // MFMA C/D
typedef __attribute__((ext_vector_type(8))) float f32x8;
typedef __attribute__((ext_vector_type(4))) unsigned short us4;

__device__ inline short bfbits(float x) {
    __hip_bfloat16 h = __float2bfloat16(x);
    short s; __builtin_memcpy(&s, &h, 2); return s;
}

// ---------------- workspace layout (float units) ----------------
// hTf  : 0        (262144 f = 524288 bf16)  fragment-ordered h^T
// s1   : 262144   (16384)
// s2   : 278528
// E2   : 294912
// E2s  : 311296
// cpos : 327680
// cneg : 344064
// thr  : 360448
// feat : 376832   (524288)
// pout : 901120   (4194304)   8 splits
// pden : 5095424  (131072)
// total 5226496 floats = 20.9 MB

// ============ K1: fused state->x1->x2->h^T(bf16 frag), s1, s2 ============
// 512 threads, 16 rows/block, 256 blocks -> 2048 waves
__global__ __launch_bounds__(512) void k_prep(
        const float* __restrict__ state,
        const float* __restrict__ W1, const float* __restrict__ b1,
        const float* __restrict__ W2, const float* __restrict__ b2,
        const float* __restrict__ Wg, const float* __restrict__ ag,
        unsigned short* __restrict__ hTf,
        float* __restrict__ s1b, float* __restrict__ s2b) {
    __shared__ float srow[16][64];
    __shared__ float x1s[16][128];
    __shared__ float x2s[16][128];
    int tid = threadIdx.x;
    int r0 = blockIdx.x * 16;
    int c = tid & 127, g = tid >> 7;          // g = row-quad 0..3

    if (tid < 256)
        ((float4*)&srow[0][0])[tid] = ((const float4*)(state + (size_t)r0 * SDIM))[tid];
    __syncthreads();

    float acc[4];
    {   // x1 = relu(state@W1+b1)
        float bb = b1[c];
#pragma unroll
        for (int r = 0; r < 4; r++) acc[r] = bb;
#pragma unroll 8
        for (int k = 0; k < SDIM; k++) {
            float w = W1[k * HID + c];
#pragma unroll
            for (int r = 0; r < 4; r++) acc[r] += w * srow[g * 4 + r][k];
        }
#pragma unroll
        for (int r = 0; r < 4; r++) x1s[g * 4 + r][c] = fmaxf(acc[r], 0.f);
    }
    __syncthreads();
    {   // x2 = relu(x1@W2+b2)
        float bb = b2[c];
#pragma unroll
        for (int r = 0; r < 4; r++) acc[r] = bb;
#pragma unroll 8
        for (int k = 0; k < HID; k++) {
            float w = W2[k * HID + c];
#pragma unroll
            for (int r = 0; r < 4; r++) acc[r] += w * x1s[g * 4 + r][k];
        }
#pragma unroll
        for (int r = 0; r < 4; r++) x2s[g * 4 + r][c] = fmaxf(acc[r], 0.f);
    }
    __syncthreads();

    // h[hd][m][f]: col c -> (hd = c>>5, f = c&31)
    int hd = c >> 5, f = c & 31;
    float hacc[4];
#pragma unroll
    for (int r = 0; r < 4; r++) hacc[r] = 0.f;
#pragma unroll 8
    for (int k = 0; k < HID; k++) {
        float w = Wg[hd * (HID * FF) + k * FF + f];
#pragma unroll
        for (int r = 0; r < 4; r++) hacc[r] += w * x2s[g * 4 + r][k];
    }

    // h^T frag order: idx(hd,f,m) =
    //   ((hd*128 + (m>>5))*2 + (f>>4))*512 + (f&15)*32 + ((m&31)>>3)*8 + (m&7)
    // BUGFIX vs R3: m&31 = (r0&31) + g*4 + r  (r0 is 16-aligned, NOT 32-aligned;
    // odd blocks land in the upper half of the 32-m fragment block)
    {
        int bn = f >> 4, fr = f & 15;
        int m31 = (r0 & 31) + g * 4;           // m&31 for r=0
        us4 pk;
#pragma unroll
        for (int r = 0; r < 4; r++) pk[r] = (unsigned short)bfbits(hacc[r]);
        *(us4*)(hTf + (size_t)((hd * 128 + (r0 >> 5)) * 2 + bn) * 512
                + fr * 32 + (m31 >> 3) * 8 + (m31 & 7)) = pk;
    }

    float a1v = ag[hd * 64 + f];
    float a2v = ag[hd * 64 + 32 + f];
#pragma unroll
    for (int r = 0; r < 4; r++) {
        float p1 = hacc[r] * a1v;
        float p2 = hacc[r] * a2v;
#pragma unroll
        for (int s = 16; s >= 1; s >>= 1) {
            p1 += __shfl_xor(p1, s, 32);
            p2 += __shfl_xor(p2, s, 32);
        }
        if (f == 0) {
            s1b[hd * NN + r0 + g * 4 + r] = p1;
            s2b[hd * NN + r0 + g * 4 + r] = p2;
        }
    }
}

// ============ K2: per-head A2 + E2/E2s/cpos/cneg/thr ============
__global__ void k_headprep(const float* __restrict__ s1b, const float* __restrict__ s2b,
                           float* __restrict__ E2, float* __restrict__ E2s,
                           float* __restrict__ cpos, float* __restrict__ cneg,
                           float* __restrict__ thr) {
    int hd = blockIdx.x;
    int tid = threadIdx.x;
    __shared__ float red[256];
    float m = -1e30f;
    for (int i = tid; i < NN; i += 256) m = fmaxf(m, s2b[hd * NN + i]);
    red[tid] = m;
    __syncthreads();
    for (int s = 128; s > 0; s >>= 1) {
        if (tid < s) red[tid] = fmaxf(red[tid], red[tid + s]);
        __syncthreads();
    }
    float A2 = red[0];
    for (int i = tid; i < NN; i += 256) {
        int idx = hd * NN + i;
        float v2 = s2b[idx];
        E2[idx]  = __expf(v2 - A2);
        E2s[idx] = __expf(0.2f * (v2 - A2));
        float v1 = s1b[idx];
        float u = v1 + A2;
        float C = (u >= 0.f) ? u : 0.2f * u;
        cpos[idx] = __expf(u - C);
        cneg[idx] = __expf(0.2f * u - C);
        thr[idx] = -v1;
    }
}

// ============ K3: attention — adj read fused, w on the fly, MFMA ============
// block: 256 thr = 4 waves (wave = head); per block: 64 n-rows x 512 m-chunk
// grid: 64 row-tiles * 8 splits = 512 blocks
__global__ __launch_bounds__(256) void k_attn(
        const int* __restrict__ adj, const unsigned short* __restrict__ hTf,
        const float* __restrict__ s2b, const float* __restrict__ E2,
        const float* __restrict__ E2s, const float* __restrict__ cposb,
        const float* __restrict__ cnegb, const float* __restrict__ thrb,
        float* __restrict__ pout, float* __restrict__ pden) {
    __shared__ unsigned int abits[64][17];   // 512-bit rows, padded stride 17

    int tid = threadIdx.x;
    int tile = blockIdx.x & 63;
    int split = blockIdx.x >> 6;
    int n0 = tile * 64, m0 = split * 512;

    {   // stage+pack adjacency: 64 rows x 512 ints -> bits
        int r = tid >> 2, sub = tid & 3;     // 4 threads/row, 128 ints each
        const int4* ap = (const int4*)(adj + (size_t)(n0 + r) * NN + m0 + sub * 128);
        unsigned int w[4] = {0u, 0u, 0u, 0u};
#pragma unroll 8
        for (int i = 0; i < 32; i++) {
            int4 a = ap[i];
            unsigned int nib = (unsigned int)(a.x != 0) | ((unsigned int)(a.y != 0) << 1)
                             | ((unsigned int)(a.z != 0) << 2) | ((unsigned int)(a.w != 0) << 3);
            w[i >> 3] |= nib << ((i & 7) * 4);
        }
#pragma unroll
        for (int j = 0; j < 4; j++) abits[r][sub * 4 + j] = w[j];
    }
    __syncthreads();

    int hd = tid >> 6, lane = tid & 63;
    int fr = lane & 15, mo = lane >> 4;

    float thrv[4], cpv[4], cnv[4];
#pragma unroll
    for (int am = 0; am < 4; am++) {
        int n = n0 + am * 16 + fr;
        thrv[am] = thrb[hd * NN + n];
        cpv[am] = cposb[hd * NN + n];
        cnv[am] = cnegb[hd * NN + n];
    }

    f32x4 acc[4][2];
#pragma unroll
    for (int am = 0; am < 4; am++)
#pragma unroll
        for (int bn = 0; bn < 2; bn++) acc[am][bn] = (f32x4){0.f, 0.f, 0.f, 0.f};
    float den[4] = {0.f, 0.f, 0.f, 0.f};

    const float* s2p = s2b + hd * NN + m0;
    const float* e2p = E2 + hd * NN + m0;
    const float* esp = E2s + hd * NN + m0;
    const unsigned short* hbase = hTf + (size_t)((hd * 128 + (m0 >> 5)) * 2) * 512 + fr * 32 + mo * 8;

#pragma unroll 2
    for (int ks = 0; ks < 16; ks++) {
        int mb = ks * 32 + mo * 8;
        f32x8 s2v = *(const f32x8*)(s2p + mb);
        f32x8 e2v = *(const f32x8*)(e2p + mb);
        f32x8 esv = *(const f32x8*)(esp + mb);
        bfrag B0 = *(const bfrag*)(hbase + ks * 1024);
        bfrag B1 = *(const bfrag*)(hbase + ks * 1024 + 512);

#pragma unroll
        for (int am = 0; am < 4; am++) {
            unsigned int bits = abits[am * 16 + fr][ks] >> (mo * 8);
            bfrag a8;
            float dsum = 0.f;
#pragma unroll
            for (int j = 0; j < 8; j++) {
                bool sel = s2v[j] >= thrv[am];
                float cc = sel ? cpv[am] : cnv[am];
                float e = sel ? e2v[j] : esv[j];
                float wv = cc * e;
                wv = ((bits >> j) & 1u) ? wv : 0.f;
                dsum += wv;
                a8[j] = bfbits(wv);
            }
            den[am] += dsum;
            acc[am][0] = __builtin_amdgcn_mfma_f32_16x16x32_bf16(a8, B0, acc[am][0], 0, 0, 0);
            acc[am][1] = __builtin_amdgcn_mfma_f32_16x16x32_bf16(a8, B1, acc[am][1], 0, 0, 0);
        }
    }

#pragma unroll
    for (int am = 0; am < 4; am++) {
        den[am] += __shfl_xor(den[am], 16);
        den[am] += __shfl_xor(den[am], 32);
    }

    float* pob = pout + ((size_t)(split * 4 + hd) * NN + n0) * FF;
#pragma unroll
    for (int am = 0; am < 4; am++) {
#pragma unroll
        for (int bn = 0; bn < 2; bn++) {
            f32x4 cv = acc[am][bn];
#pragma unroll
            for (int r = 0; r < 4; r++)
                pob[(am * 16 + mo * 4 + r) * FF + bn * 16 + fr] = cv[r];
        }
        if (mo == 0)
            pden[(size_t)(split * 4 + hd) * NN + n0 + am * 16 + fr] = den[am];
    }
}

// ============ K4: reduce partials -> feat (n, hd*32+f) ============
__global__ void k_reduce(const float* __restrict__ pout, const float* __restrict__ pden,
                         float* __restrict__ feat) {
    int gid = blockIdx.x * 256 + threadIdx.x;
    int f = gid & 31;
    int n = (gid >> 5) & (NN - 1);
    int hd = gid >> 17;
    float den = 0.f;
#pragma unroll
    for (int s = 0; s < NSPLIT; s++) den += pden[(size_t)(s * 4 + hd) * NN + n];
    float o = 0.f;
#pragma unroll
    for (int s = 0; s < NSPLIT; s++) o += pout[((size_t)(s * 4 + hd) * NN + n) * FF + f];
    feat[(size_t)n * HID + hd * FF + f] = o / fmaxf(den, 1e-30f);
}

// ============ K5: policy head (512 thr, 16 rows/block) ============
__global__ __launch_bounds__(512) void k_policy(
        const float* __restrict__ feat,
        const float* __restrict__ Wp1, const float* __restrict__ bp1,
        const float* __restrict__ Wp2, const float* __restrict__ bp2,
        float* __restrict__ out) {
    __shared__ float fr[16][128];
    __shared__ float ph[16][128];
    int tid = threadIdx.x;
    int r0 = blockIdx.x * 16;
    ((float4*)&fr[0][0])[tid] = ((const float4*)(feat + (size_t)r0 * HID))[tid];
    __syncthreads();
    int c = tid & 127, g = tid >> 7;
    float acc[4];
    float bb = bp1[c];
#pragma unroll
    for (int r = 0; r < 4; r++) acc[r] = bb;
#pragma unroll 8
    for (int k = 0; k < HID; k++) {
        float w = Wp1[k * HID + c];
#pragma unroll
        for (int r = 0; r < 4; r++) acc[r] += w * fr[g * 4 + r][k];
    }
#pragma unroll
    for (int r = 0; r < 4; r++) ph[g * 4 + r][c] = fmaxf(acc[r], 0.f);
    __syncthreads();

    int c2 = tid & 31, r = tid >> 5;   // one output each: 16 rows x 32 cols
    float lacc = bp2[c2];
#pragma unroll 8
    for (int k = 0; k < HID; k++) lacc += ph[r][k] * Wp2[k * 32 + c2];
    float mx = lacc;
#pragma unroll
    for (int s = 16; s >= 1; s >>= 1) mx = fmaxf(mx, __shfl_xor(mx, s, 32));
    float e = __expf(lacc - mx);
    float sm = e;
#pragma unroll
    for (int s = 16; s >= 1; s >>= 1) sm += __shfl_xor(sm, s, 32);
    out[(size_t)(r0 + r) * 32 + c2] = e / sm;
}

// ============ K6: value head (512 thr, 16 rows/block) ============
__global__ __launch_bounds__(512) void k_value(
        const float* __restrict__ feat,
        const float* __restrict__ Wv1, const float* __restrict__ bv1,
        const float* __restrict__ Wv2, const float* __restrict__ bv2,
        float* __restrict__ out) {
    __shared__ float fr[16][128];
    __shared__ float vh[16][128];
    int tid = threadIdx.x;
    int r0 = blockIdx.x * 16;
    ((float4*)&fr[0][0])[tid] = ((const float4*)(feat + (size_t)r0 * HID))[tid];
    __syncthreads();
    int c = tid & 127, g = tid >> 7;
    float acc[4];
    float bb = bv1[c];
#pragma unroll
    for (int r = 0; r < 4; r++) acc[r] = bb;
#pragma unroll 8
    for (int k = 0; k < HID; k++) {
        float w = Wv1[k * HID + c];
#pragma unroll
        for (int r = 0; r < 4; r++) acc[r] += w * fr[g * 4 + r][k];
    }
#pragma unroll
    for (int r = 0; r < 4; r++) vh[g * 4 + r][c] = fmaxf(acc[r], 0.f);
    __syncthreads();

    int c2 = tid & 31, r = tid >> 5;
    float p = 0.f;
#pragma unroll
    for (int j = 0; j < 4; j++) p += vh[r][c2 + j * 32] * Wv2[c2 + j * 32];
#pragma unroll
    for (int s = 16; s >= 1; s >>= 1) p += __shfl_xor(p, s, 32);
    if (c2 == 0) out[131072 + r0 + r] = p + bv2[0];
}

extern "C" void kernel_launch(void* const* d_in, const int* in_sizes, int n_in,
                              void* d_out, int out_size, void* d_ws, size_t ws_size,
                              hipStream_t stream) {
    const float* state = (const float*)d_in[0];
    const int*   adj   = (const int*)d_in[1];
    const float* W1  = (const float*)d_in[2];
    const float* b1  = (const float*)d_in[3];
    const float* W2  = (const float*)d_in[4];
    const float* b2  = (const float*)d_in[5];
    const float* Wg  = (const float*)d_in[6];
    const float* ag  = (const float*)d_in[7];
    const float* Wp1 = (const float*)d_in[8];
    const float* bp1 = (const float*)d_in[9];
    const float* Wp2 = (const float*)d_in[10];
    const float* bp2 = (const float*)d_in[11];
    const float* Wv1 = (const float*)d_in[12];
    const float* bv1 = (const float*)d_in[13];
    const float* Wv2 = (const float*)d_in[14];
    const float* bv2 = (const float*)d_in[15];
    float* out = (float*)d_out;
    float* ws = (float*)d_ws;

    unsigned short* hTf = (unsigned short*)ws;          // 524288 bf16
    float* s1b  = ws + 262144;
    float* s2b  = ws + 278528;
    float* E2   = ws + 294912;
    float* E2s  = ws + 311296;
    float* cpos = ws + 327680;
    float* cneg = ws + 344064;
    float* thr  = ws + 360448;
    float* feat = ws + 376832;
    float* pout = ws + 901120;
    float* pden = ws + 5095424;

    hipLaunchKernelGGL(k_prep, dim3(NN / 16), dim3(512), 0, stream,
                       state, W1, b1, W2, b2, Wg, ag, hTf, s1b, s2b);
    hipLaunchKernelGGL(k_headprep, dim3(HEADS), dim3(256), 0, stream,
                       s1b, s2b, E2, E2s, cpos, cneg, thr);
    hipLaunchKernelGGL(k_attn, dim3(64 * NSPLIT), dim3(256), 0, stream,
                       adj, hTf, s2b, E2, E2s, cpos, cneg, thr, pout, pden);
    hipLaunchKernelGGL(k_reduce, dim3((HEADS * NN * FF) / 256), dim3(256), 0, stream,
                       pout, pden, feat);
    hipLaunchKernelGGL(k_policy, dim3(NN / 16), dim3(512), 0, stream,
                       feat, Wp1, bp1, Wp2, bp2, out);
    hipLaunchKernelGGL(k_value, dim3(NN / 16), dim3(512), 0, stream,
                       feat, Wv1, bv1, Wv2, bv2, out);
}

// Round 5
// 81.575 us; speedup vs baseline: 2.1276x; 1.0912x over previous
//
#include <hip/hip_runtime.h>
#include <hip/hip_bf16.h>

#define NN 4096
#define SDIM 64
#define HID 128
#define HEADS 4
#define FF 32
#define NSPLIT 16

typedef __attribute__((ext_vector_type(8))) short bfrag;      // 8 bf16 = 4 VGPR (MFMA A/B)
typedef __attribute__((ext_vector_type(4))) float f32x4;      // MFMA C/D
typedef __attribute__((ext_vector_type(8))) float f32x8;
typedef __attribute__((ext_vector_type(4))) unsigned short us4;

__device__ inline short bfbits(float x) {
    __hip_bfloat16 h = __float2bfloat16(x);
    short s; __builtin_memcpy(&s, &h, 2); return s;
}

// ---------------- workspace layout (float units) ----------------
// hTf  : 0        (262144 f = 524288 bf16)  fragment-ordered h^T
// s1   : 262144   (16384)
// s2   : 278528
// E2   : 294912
// E2s  : 311296
// cpos : 327680
// cneg : 344064
// thr  : 360448
// abit : 376832   (524288 f = 2 MB bits)  -- overlapped with feat (abit dead
// feat : 376832   (524288)                   before k_reduce writes feat)
// pout : 901120   (8388608)  16 splits
// pden : 9289728  (262144)
// total 9551872 floats = 38.2 MB (proven size in R1/R2)

// ============ K1: grid-partitioned fusion of prep (blocks 0..255)
//                  and adjacency bit-pack (blocks 256..4351) ============
__global__ __launch_bounds__(512) void k_prep_pack(
        const float* __restrict__ state,
        const float* __restrict__ W1, const float* __restrict__ b1,
        const float* __restrict__ W2, const float* __restrict__ b2,
        const float* __restrict__ Wg, const float* __restrict__ ag,
        const int* __restrict__ adj,
        unsigned short* __restrict__ hTf,
        float* __restrict__ s1b, float* __restrict__ s2b,
        unsigned int* __restrict__ abit) {
    int tid = threadIdx.x;

    if (blockIdx.x >= 256) {
        // ---- pack branch: one adjacency row per block, 8 ints/thread -> 1 byte ----
        int r = blockIdx.x - 256;
        const int4* ap = (const int4*)(adj + (size_t)r * NN + tid * 8);
        int4 a0 = ap[0], a1 = ap[1];
        unsigned int b = (unsigned int)(a0.x != 0)
                       | ((unsigned int)(a0.y != 0) << 1)
                       | ((unsigned int)(a0.z != 0) << 2)
                       | ((unsigned int)(a0.w != 0) << 3)
                       | ((unsigned int)(a1.x != 0) << 4)
                       | ((unsigned int)(a1.y != 0) << 5)
                       | ((unsigned int)(a1.z != 0) << 6)
                       | ((unsigned int)(a1.w != 0) << 7);
        ((unsigned char*)abit)[(size_t)r * 512 + tid] = (unsigned char)b;
        return;
    }

    // ---- prep branch: 16 rows/block (R4-verified body) ----
    __shared__ float srow[16][64];
    __shared__ float x1s[16][128];
    __shared__ float x2s[16][128];
    int r0 = blockIdx.x * 16;
    int c = tid & 127, g = tid >> 7;          // g = row-quad 0..3

    if (tid < 256)
        ((float4*)&srow[0][0])[tid] = ((const float4*)(state + (size_t)r0 * SDIM))[tid];
    __syncthreads();

    float acc[4];
    {   // x1 = relu(state@W1+b1)
        float bb = b1[c];
#pragma unroll
        for (int r = 0; r < 4; r++) acc[r] = bb;
#pragma unroll 8
        for (int k = 0; k < SDIM; k++) {
            float w = W1[k * HID + c];
#pragma unroll
            for (int r = 0; r < 4; r++) acc[r] += w * srow[g * 4 + r][k];
        }
#pragma unroll
        for (int r = 0; r < 4; r++) x1s[g * 4 + r][c] = fmaxf(acc[r], 0.f);
    }
    __syncthreads();
    {   // x2 = relu(x1@W2+b2)
        float bb = b2[c];
#pragma unroll
        for (int r = 0; r < 4; r++) acc[r] = bb;
#pragma unroll 8
        for (int k = 0; k < HID; k++) {
            float w = W2[k * HID + c];
#pragma unroll
            for (int r = 0; r < 4; r++) acc[r] += w * x1s[g * 4 + r][k];
        }
#pragma unroll
        for (int r = 0; r < 4; r++) x2s[g * 4 + r][c] = fmaxf(acc[r], 0.f);
    }
    __syncthreads();

    int hd = c >> 5, f = c & 31;
    float hacc[4];
#pragma unroll
    for (int r = 0; r < 4; r++) hacc[r] = 0.f;
#pragma unroll 8
    for (int k = 0; k < HID; k++) {
        float w = Wg[hd * (HID * FF) + k * FF + f];
#pragma unroll
        for (int r = 0; r < 4; r++) hacc[r] += w * x2s[g * 4 + r][k];
    }

    // h^T frag order: idx(hd,f,m) =
    //   ((hd*128 + (m>>5))*2 + (f>>4))*512 + (f&15)*32 + ((m&31)>>3)*8 + (m&7)
    // m&31 = (r0&31) + g*4 + r   (r0 is 16-aligned, not 32-aligned)
    {
        int bn = f >> 4, fr = f & 15;
        int m31 = (r0 & 31) + g * 4;
        us4 pk;
#pragma unroll
        for (int r = 0; r < 4; r++) pk[r] = (unsigned short)bfbits(hacc[r]);
        *(us4*)(hTf + (size_t)((hd * 128 + (r0 >> 5)) * 2 + bn) * 512
                + fr * 32 + (m31 >> 3) * 8 + (m31 & 7)) = pk;
    }

    float a1v = ag[hd * 64 + f];
    float a2v = ag[hd * 64 + 32 + f];
#pragma unroll
    for (int r = 0; r < 4; r++) {
        float p1 = hacc[r] * a1v;
        float p2 = hacc[r] * a2v;
#pragma unroll
        for (int s = 16; s >= 1; s >>= 1) {
            p1 += __shfl_xor(p1, s, 32);
            p2 += __shfl_xor(p2, s, 32);
        }
        if (f == 0) {
            s1b[hd * NN + r0 + g * 4 + r] = p1;
            s2b[hd * NN + r0 + g * 4 + r] = p2;
        }
    }
}

// ============ K2: per-head A2 + E2/E2s/cpos/cneg/thr ============
__global__ void k_headprep(const float* __restrict__ s1b, const float* __restrict__ s2b,
                           float* __restrict__ E2, float* __restrict__ E2s,
                           float* __restrict__ cpos, float* __restrict__ cneg,
                           float* __restrict__ thr) {
    int hd = blockIdx.x;
    int tid = threadIdx.x;
    __shared__ float red[256];
    float m = -1e30f;
    for (int i = tid; i < NN; i += 256) m = fmaxf(m, s2b[hd * NN + i]);
    red[tid] = m;
    __syncthreads();
    for (int s = 128; s > 0; s >>= 1) {
        if (tid < s) red[tid] = fmaxf(red[tid], red[tid + s]);
        __syncthreads();
    }
    float A2 = red[0];
    for (int i = tid; i < NN; i += 256) {
        int idx = hd * NN + i;
        float v2 = s2b[idx];
        E2[idx]  = __expf(v2 - A2);
        E2s[idx] = __expf(0.2f * (v2 - A2));
        float v1 = s1b[idx];
        float u = v1 + A2;
        float C = (u >= 0.f) ? u : 0.2f * u;
        cpos[idx] = __expf(u - C);
        cneg[idx] = __expf(0.2f * u - C);
        thr[idx] = -v1;
    }
}

// ============ K3: attention — w built on the fly, MFMA (R2-verified) ============
// block: 256 thr = 4 waves (wave = head); per block: 64 n-rows x 256 m-chunk
// grid: 64 row-tiles * 16 splits = 1024 blocks
__global__ __launch_bounds__(256) void k_attn(
        const unsigned int* __restrict__ abit, const unsigned short* __restrict__ hTf,
        const float* __restrict__ s2b, const float* __restrict__ E2,
        const float* __restrict__ E2s, const float* __restrict__ cposb,
        const float* __restrict__ cnegb, const float* __restrict__ thrb,
        float* __restrict__ pout, float* __restrict__ pden) {
    __shared__ unsigned int abits[64][9];   // 256-bit rows, padded stride 9

    int tid = threadIdx.x;
    int tile = blockIdx.x & 63;
    int split = blockIdx.x >> 6;
    int n0 = tile * 64, m0 = split * 256;

    {   // stage bitmask chunk: 64 rows x 8 words
        int r = tid >> 2, q = tid & 3;
        const unsigned int* src = abit + (size_t)(n0 + r) * 128 + split * 8 + q * 2;
        abits[r][q * 2 + 0] = src[0];
        abits[r][q * 2 + 1] = src[1];
    }
    __syncthreads();

    int hd = tid >> 6, lane = tid & 63;
    int fr = lane & 15, mo = lane >> 4;

    float thrv[4], cpv[4], cnv[4];
#pragma unroll
    for (int am = 0; am < 4; am++) {
        int n = n0 + am * 16 + fr;
        thrv[am] = thrb[hd * NN + n];
        cpv[am] = cposb[hd * NN + n];
        cnv[am] = cnegb[hd * NN + n];
    }

    f32x4 acc[4][2];
#pragma unroll
    for (int am = 0; am < 4; am++)
#pragma unroll
        for (int bn = 0; bn < 2; bn++) acc[am][bn] = (f32x4){0.f, 0.f, 0.f, 0.f};
    float den[4] = {0.f, 0.f, 0.f, 0.f};

    const float* s2p = s2b + hd * NN + m0;
    const float* e2p = E2 + hd * NN + m0;
    const float* esp = E2s + hd * NN + m0;
    const unsigned short* hbase = hTf + (size_t)((hd * 128 + (m0 >> 5)) * 2) * 512 + fr * 32 + mo * 8;

#pragma unroll 2
    for (int ks = 0; ks < 8; ks++) {
        int mb = ks * 32 + mo * 8;
        f32x8 s2v = *(const f32x8*)(s2p + mb);
        f32x8 e2v = *(const f32x8*)(e2p + mb);
        f32x8 esv = *(const f32x8*)(esp + mb);
        bfrag B0 = *(const bfrag*)(hbase + ks * 1024);
        bfrag B1 = *(const bfrag*)(hbase + ks * 1024 + 512);

#pragma unroll
        for (int am = 0; am < 4; am++) {
            unsigned int bits = abits[am * 16 + fr][ks] >> (mo * 8);
            bfrag a8;
            float dsum = 0.f;
#pragma unroll
            for (int j = 0; j < 8; j++) {
                bool sel = s2v[j] >= thrv[am];
                float cc = sel ? cpv[am] : cnv[am];
                float e = sel ? e2v[j] : esv[j];
                float wv = cc * e;
                wv = ((bits >> j) & 1u) ? wv : 0.f;
                dsum += wv;
                a8[j] = bfbits(wv);
            }
            den[am] += dsum;
            acc[am][0] = __builtin_amdgcn_mfma_f32_16x16x32_bf16(a8, B0, acc[am][0], 0, 0, 0);
            acc[am][1] = __builtin_amdgcn_mfma_f32_16x16x32_bf16(a8, B1, acc[am][1], 0, 0, 0);
        }
    }

#pragma unroll
    for (int am = 0; am < 4; am++) {
        den[am] += __shfl_xor(den[am], 16);
        den[am] += __shfl_xor(den[am], 32);
    }

    float* pob = pout + ((size_t)(split * 4 + hd) * NN + n0) * FF;
#pragma unroll
    for (int am = 0; am < 4; am++) {
#pragma unroll
        for (int bn = 0; bn < 2; bn++) {
            f32x4 cv = acc[am][bn];
#pragma unroll
            for (int r = 0; r < 4; r++)
                pob[(am * 16 + mo * 4 + r) * FF + bn * 16 + fr] = cv[r];
        }
        if (mo == 0)
            pden[(size_t)(split * 4 + hd) * NN + n0 + am * 16 + fr] = den[am];
    }
}

// ============ K4: reduce partials -> feat (n, hd*32+f) ============
__global__ void k_reduce(const float* __restrict__ pout, const float* __restrict__ pden,
                         float* __restrict__ feat) {
    int gid = blockIdx.x * 256 + threadIdx.x;
    int f = gid & 31;
    int n = (gid >> 5) & (NN - 1);
    int hd = gid >> 17;
    float den = 0.f;
#pragma unroll
    for (int s = 0; s < NSPLIT; s++) den += pden[(size_t)(s * 4 + hd) * NN + n];
    float o = 0.f;
#pragma unroll
    for (int s = 0; s < NSPLIT; s++) o += pout[((size_t)(s * 4 + hd) * NN + n) * FF + f];
    feat[(size_t)n * HID + hd * FF + f] = o / fmaxf(den, 1e-30f);
}

// ============ K5: grid-partitioned policy (blocks 0..255) + value (256..511) ============
__global__ __launch_bounds__(512) void k_polval(
        const float* __restrict__ feat,
        const float* __restrict__ Wp1, const float* __restrict__ bp1,
        const float* __restrict__ Wp2, const float* __restrict__ bp2,
        const float* __restrict__ Wv1, const float* __restrict__ bv1,
        const float* __restrict__ Wv2, const float* __restrict__ bv2,
        float* __restrict__ out) {
    __shared__ float fr[16][128];
    __shared__ float hh[16][128];
    int tid = threadIdx.x;
    bool is_val = blockIdx.x >= 256;
    int r0 = (is_val ? blockIdx.x - 256 : blockIdx.x) * 16;
    const float* Wa = is_val ? Wv1 : Wp1;
    const float* ba = is_val ? bv1 : bp1;

    ((float4*)&fr[0][0])[tid] = ((const float4*)(feat + (size_t)r0 * HID))[tid];
    __syncthreads();
    int c = tid & 127, g = tid >> 7;
    float acc[4];
    float bb = ba[c];
#pragma unroll
    for (int r = 0; r < 4; r++) acc[r] = bb;
#pragma unroll 8
    for (int k = 0; k < HID; k++) {
        float w = Wa[k * HID + c];
#pragma unroll
        for (int r = 0; r < 4; r++) acc[r] += w * fr[g * 4 + r][k];
    }
#pragma unroll
    for (int r = 0; r < 4; r++) hh[g * 4 + r][c] = fmaxf(acc[r], 0.f);
    __syncthreads();

    int c2 = tid & 31, r = tid >> 5;
    if (!is_val) {
        float lacc = bp2[c2];
#pragma unroll 8
        for (int k = 0; k < HID; k++) lacc += hh[r][k] * Wp2[k * 32 + c2];
        float mx = lacc;
#pragma unroll
        for (int s = 16; s >= 1; s >>= 1) mx = fmaxf(mx, __shfl_xor(mx, s, 32));
        float e = __expf(lacc - mx);
        float sm = e;
#pragma unroll
        for (int s = 16; s >= 1; s >>= 1) sm += __shfl_xor(sm, s, 32);
        out[(size_t)(r0 + r) * 32 + c2] = e / sm;
    } else {
        float p = 0.f;
#pragma unroll
        for (int j = 0; j < 4; j++) p += hh[r][c2 + j * 32] * Wv2[c2 + j * 32];
#pragma unroll
        for (int s = 16; s >= 1; s >>= 1) p += __shfl_xor(p, s, 32);
        if (c2 == 0) out[131072 + r0 + r] = p + bv2[0];
    }
}

extern "C" void kernel_launch(void* const* d_in, const int* in_sizes, int n_in,
                              void* d_out, int out_size, void* d_ws, size_t ws_size,
                              hipStream_t stream) {
    const float* state = (const float*)d_in[0];
    const int*   adj   = (const int*)d_in[1];
    const float* W1  = (const float*)d_in[2];
    const float* b1  = (const float*)d_in[3];
    const float* W2  = (const float*)d_in[4];
    const float* b2  = (const float*)d_in[5];
    const float* Wg  = (const float*)d_in[6];
    const float* ag  = (const float*)d_in[7];
    const float* Wp1 = (const float*)d_in[8];
    const float* bp1 = (const float*)d_in[9];
    const float* Wp2 = (const float*)d_in[10];
    const float* bp2 = (const float*)d_in[11];
    const float* Wv1 = (const float*)d_in[12];
    const float* bv1 = (const float*)d_in[13];
    const float* Wv2 = (const float*)d_in[14];
    const float* bv2 = (const float*)d_in[15];
    float* out = (float*)d_out;
    float* ws = (float*)d_ws;

    unsigned short* hTf = (unsigned short*)ws;          // 524288 bf16
    float* s1b  = ws + 262144;
    float* s2b  = ws + 278528;
    float* E2   = ws + 294912;
    float* E2s  = ws + 311296;
    float* cpos = ws + 327680;
    float* cneg = ws + 344064;
    float* thr  = ws + 360448;
    unsigned int* abit = (unsigned int*)(ws + 376832);  // 2 MB
    float* feat = ws + 376832;                          // overlaps abit (dead by then)
    float* pout = ws + 901120;
    float* pden = ws + 9289728;

    hipLaunchKernelGGL(k_prep_pack, dim3(256 + NN), dim3(512), 0, stream,
                       state, W1, b1, W2, b2, Wg, ag, adj, hTf, s1b, s2b, abit);
    hipLaunchKernelGGL(k_headprep, dim3(HEADS), dim3(256), 0, stream,
                       s1b, s2b, E2, E2s, cpos, cneg, thr);
    hipLaunchKernelGGL(k_attn, dim3(64 * NSPLIT), dim3(256), 0, stream,
                       abit, hTf, s2b, E2, E2s, cpos, cneg, thr, pout, pden);
    hipLaunchKernelGGL(k_reduce, dim3((HEADS * NN * FF) / 256), dim3(256), 0, stream,
                       pout, pden, feat);
    hipLaunchKernelGGL(k_polval, dim3(512), dim3(512), 0, stream,
                       feat, Wp1, bp1, Wp2, bp2, Wv1, bv1, Wv2, bv2, out);
}

// Round 6
// 80.342 us; speedup vs baseline: 2.1602x; 1.0153x over previous
//
#include <hip/hip_runtime.h>
#include <hip/hip_bf16.h>
#include <hip/hip_fp16.h>

#define NN 4096
#define SDIM 64
#define HID 128
#define HEADS 4
#define FF 32
#define NSPLIT 32

typedef __attribute__((ext_vector_type(8))) short bfrag;      // 8 bf16 = 4 VGPR (MFMA A/B)
typedef __attribute__((ext_vector_type(4))) float f32x4;      // MFMA C/D
typedef __attribute__((ext_vector_type(8))) float f32x8;
typedef __attribute__((ext_vector_type(4))) unsigned short us4;

__device__ inline short bfbits(float x) {
    __hip_bfloat16 h = __float2bfloat16(x);
    short s; __builtin_memcpy(&s, &h, 2); return s;
}

// ---------------- workspace layout (float units) ----------------
// hTf  : 0        (262144 f = 524288 bf16)  fragment-ordered h^T
// s1   : 262144   s2: 278528  E2: 294912  E2s: 311296
// cpos : 327680   cneg: 344064  thr: 360448      (16384 each)
// abit : 376832   (524288 f = 2 MB bits)  -- overlapped with feat (abit dead
// feat : 376832   (524288)                   before k_reduce writes feat)
// pout : 901120   (8388608 f-units = 16.8M fp16)   32 splits
// pden : 9289728  (524288)
// total 9814016 floats = 39.3 MB

// ============ K1: grid-partitioned prep (blocks 0..511, 8 rows each)
//                  + adjacency bit-pack (blocks 512..4607, 1 row each) ============
__global__ __launch_bounds__(256) void k_prep_pack(
        const float* __restrict__ state,
        const float* __restrict__ W1, const float* __restrict__ b1,
        const float* __restrict__ W2, const float* __restrict__ b2,
        const float* __restrict__ Wg, const float* __restrict__ ag,
        const int* __restrict__ adj,
        unsigned short* __restrict__ hTf,
        float* __restrict__ s1b, float* __restrict__ s2b,
        unsigned int* __restrict__ abit) {
    int tid = threadIdx.x;

    if (blockIdx.x >= 512) {
        // ---- pack branch (R2-verified): thread t packs 16 ints -> ushort ----
        int r = blockIdx.x - 512;
        const int4* ap = (const int4*)(adj + (size_t)r * NN + tid * 16);
        unsigned int b = 0;
#pragma unroll
        for (int i = 0; i < 4; i++) {
            int4 a = ap[i];
            b |= (unsigned int)(a.x != 0) << (i * 4 + 0);
            b |= (unsigned int)(a.y != 0) << (i * 4 + 1);
            b |= (unsigned int)(a.z != 0) << (i * 4 + 2);
            b |= (unsigned int)(a.w != 0) << (i * 4 + 3);
        }
        ((unsigned short*)abit)[r * 256 + tid] = (unsigned short)b;
        return;
    }

    // ---- prep branch: 8 rows/block, 256 threads ----
    __shared__ float srow[8][64];
    __shared__ float x1s[8][128];
    __shared__ float x2s[8][128];
    int r0 = blockIdx.x * 8;
    int c = tid & 127, g = tid >> 7;          // g = row-quad 0..1

    if (tid < 128)
        ((float4*)&srow[0][0])[tid] = ((const float4*)(state + (size_t)r0 * SDIM))[tid];
    __syncthreads();

    float acc[4];
    {   // x1 = relu(state@W1+b1)
        float bb = b1[c];
#pragma unroll
        for (int r = 0; r < 4; r++) acc[r] = bb;
#pragma unroll 8
        for (int k = 0; k < SDIM; k++) {
            float w = W1[k * HID + c];
#pragma unroll
            for (int r = 0; r < 4; r++) acc[r] += w * srow[g * 4 + r][k];
        }
#pragma unroll
        for (int r = 0; r < 4; r++) x1s[g * 4 + r][c] = fmaxf(acc[r], 0.f);
    }
    __syncthreads();
    {   // x2 = relu(x1@W2+b2)
        float bb = b2[c];
#pragma unroll
        for (int r = 0; r < 4; r++) acc[r] = bb;
#pragma unroll 8
        for (int k = 0; k < HID; k++) {
            float w = W2[k * HID + c];
#pragma unroll
            for (int r = 0; r < 4; r++) acc[r] += w * x1s[g * 4 + r][k];
        }
#pragma unroll
        for (int r = 0; r < 4; r++) x2s[g * 4 + r][c] = fmaxf(acc[r], 0.f);
    }
    __syncthreads();

    int hd = c >> 5, f = c & 31;
    float hacc[4];
#pragma unroll
    for (int r = 0; r < 4; r++) hacc[r] = 0.f;
#pragma unroll 8
    for (int k = 0; k < HID; k++) {
        float w = Wg[hd * (HID * FF) + k * FF + f];
#pragma unroll
        for (int r = 0; r < 4; r++) hacc[r] += w * x2s[g * 4 + r][k];
    }

    // h^T frag order: idx(hd,f,m) =
    //   ((hd*128 + (m>>5))*2 + (f>>4))*512 + (f&15)*32 + ((m&31)>>3)*8 + (m&7)
    // m&31 = (r0&31) + g*4 + r   (r0 is 8-aligned; rows r=0..3 contiguous,
    // base multiple of 4 so the us4 store stays inside one 8-m sub-block)
    {
        int bn = f >> 4, fr = f & 15;
        int m31 = (r0 & 31) + g * 4;
        us4 pk;
#pragma unroll
        for (int r = 0; r < 4; r++) pk[r] = (unsigned short)bfbits(hacc[r]);
        *(us4*)(hTf + (size_t)((hd * 128 + (r0 >> 5)) * 2 + bn) * 512
                + fr * 32 + (m31 >> 3) * 8 + (m31 & 7)) = pk;
    }

    float a1v = ag[hd * 64 + f];
    float a2v = ag[hd * 64 + 32 + f];
#pragma unroll
    for (int r = 0; r < 4; r++) {
        float p1 = hacc[r] * a1v;
        float p2 = hacc[r] * a2v;
#pragma unroll
        for (int s = 16; s >= 1; s >>= 1) {
            p1 += __shfl_xor(p1, s, 32);
            p2 += __shfl_xor(p2, s, 32);
        }
        if (f == 0) {
            s1b[hd * NN + r0 + g * 4 + r] = p1;
            s2b[hd * NN + r0 + g * 4 + r] = p2;
        }
    }
}

// ============ K2: per-head A2 + E2/E2s/cpos/cneg/thr ============
__global__ void k_headprep(const float* __restrict__ s1b, const float* __restrict__ s2b,
                           float* __restrict__ E2, float* __restrict__ E2s,
                           float* __restrict__ cpos, float* __restrict__ cneg,
                           float* __restrict__ thr) {
    int hd = blockIdx.x;
    int tid = threadIdx.x;
    __shared__ float red[256];
    float m = -1e30f;
    for (int i = tid; i < NN; i += 256) m = fmaxf(m, s2b[hd * NN + i]);
    red[tid] = m;
    __syncthreads();
    for (int s = 128; s > 0; s >>= 1) {
        if (tid < s) red[tid] = fmaxf(red[tid], red[tid + s]);
        __syncthreads();
    }
    float A2 = red[0];
    for (int i = tid; i < NN; i += 256) {
        int idx = hd * NN + i;
        float v2 = s2b[idx];
        E2[idx]  = __expf(v2 - A2);
        E2s[idx] = __expf(0.2f * (v2 - A2));
        float v1 = s1b[idx];
        float u = v1 + A2;
        float C = (u >= 0.f) ? u : 0.2f * u;
        cpos[idx] = __expf(u - C);
        cneg[idx] = __expf(0.2f * u - C);
        thr[idx] = -v1;
    }
}

// ============ K3: attention — w built on the fly, MFMA ============
// block: 256 thr = 4 waves (wave = head); per block: 64 n-rows x 128 m-chunk
// grid: 64 row-tiles * 32 splits = 2048 blocks (8/CU)
__global__ __launch_bounds__(256) void k_attn(
        const unsigned int* __restrict__ abit, const unsigned short* __restrict__ hTf,
        const float* __restrict__ s2b, const float* __restrict__ E2,
        const float* __restrict__ E2s, const float* __restrict__ cposb,
        const float* __restrict__ cnegb, const float* __restrict__ thrb,
        __half* __restrict__ pout, float* __restrict__ pden) {
    __shared__ unsigned int abits[64][5];   // 128-bit rows, padded stride 5

    int tid = threadIdx.x;
    int tile = blockIdx.x & 63;
    int split = blockIdx.x >> 6;
    int n0 = tile * 64, m0 = split * 128;

    {   // stage bitmask chunk: 64 rows x 4 words, one word per thread
        int r = tid >> 2, q = tid & 3;
        abits[r][q] = abit[(size_t)(n0 + r) * 128 + split * 4 + q];
    }
    __syncthreads();

    int hd = tid >> 6, lane = tid & 63;
    int fr = lane & 15, mo = lane >> 4;

    float thrv[4], cpv[4], cnv[4];
#pragma unroll
    for (int am = 0; am < 4; am++) {
        int n = n0 + am * 16 + fr;
        thrv[am] = thrb[hd * NN + n];
        cpv[am] = cposb[hd * NN + n];
        cnv[am] = cnegb[hd * NN + n];
    }

    f32x4 acc[4][2];
#pragma unroll
    for (int am = 0; am < 4; am++)
#pragma unroll
        for (int bn = 0; bn < 2; bn++) acc[am][bn] = (f32x4){0.f, 0.f, 0.f, 0.f};
    float den[4] = {0.f, 0.f, 0.f, 0.f};

    const float* s2p = s2b + hd * NN + m0;
    const float* e2p = E2 + hd * NN + m0;
    const float* esp = E2s + hd * NN + m0;
    const unsigned short* hbase = hTf + (size_t)((hd * 128 + (m0 >> 5)) * 2) * 512 + fr * 32 + mo * 8;

#pragma unroll
    for (int ks = 0; ks < 4; ks++) {
        int mb = ks * 32 + mo * 8;
        f32x8 s2v = *(const f32x8*)(s2p + mb);
        f32x8 e2v = *(const f32x8*)(e2p + mb);
        f32x8 esv = *(const f32x8*)(esp + mb);
        bfrag B0 = *(const bfrag*)(hbase + ks * 1024);
        bfrag B1 = *(const bfrag*)(hbase + ks * 1024 + 512);

#pragma unroll
        for (int am = 0; am < 4; am++) {
            unsigned int bits = abits[am * 16 + fr][ks] >> (mo * 8);
            bfrag a8;
            float dsum = 0.f;
#pragma unroll
            for (int j = 0; j < 8; j++) {
                bool sel = s2v[j] >= thrv[am];
                float cc = sel ? cpv[am] : cnv[am];
                float e = sel ? e2v[j] : esv[j];
                float wv = cc * e;
                wv = ((bits >> j) & 1u) ? wv : 0.f;
                dsum += wv;
                a8[j] = bfbits(wv);
            }
            den[am] += dsum;
            acc[am][0] = __builtin_amdgcn_mfma_f32_16x16x32_bf16(a8, B0, acc[am][0], 0, 0, 0);
            acc[am][1] = __builtin_amdgcn_mfma_f32_16x16x32_bf16(a8, B1, acc[am][1], 0, 0, 0);
        }
    }

#pragma unroll
    for (int am = 0; am < 4; am++) {
        den[am] += __shfl_xor(den[am], 16);
        den[am] += __shfl_xor(den[am], 32);
    }

    __half* pob = pout + ((size_t)(split * 4 + hd) * NN + n0) * FF;
#pragma unroll
    for (int am = 0; am < 4; am++) {
#pragma unroll
        for (int bn = 0; bn < 2; bn++) {
            f32x4 cv = acc[am][bn];
#pragma unroll
            for (int r = 0; r < 4; r++)
                pob[(am * 16 + mo * 4 + r) * FF + bn * 16 + fr] = __float2half(cv[r]);
        }
        if (mo == 0)
            pden[(size_t)(split * 4 + hd) * NN + n0 + am * 16 + fr] = den[am];
    }
}

// ============ K4: reduce partials -> feat (n, hd*32+f) ============
__global__ void k_reduce(const __half* __restrict__ pout, const float* __restrict__ pden,
                         float* __restrict__ feat) {
    int gid = blockIdx.x * 256 + threadIdx.x;
    int f = gid & 31;
    int n = (gid >> 5) & (NN - 1);
    int hd = gid >> 17;
    float den = 0.f;
#pragma unroll
    for (int s = 0; s < NSPLIT; s++) den += pden[(size_t)(s * 4 + hd) * NN + n];
    float o = 0.f;
#pragma unroll
    for (int s = 0; s < NSPLIT; s++)
        o += __half2float(pout[((size_t)(s * 4 + hd) * NN + n) * FF + f]);
    feat[(size_t)n * HID + hd * FF + f] = o / fmaxf(den, 1e-30f);
}

// ============ K5: grid-partitioned policy (blocks 0..255) + value (256..511) ============
__global__ __launch_bounds__(512) void k_polval(
        const float* __restrict__ feat,
        const float* __restrict__ Wp1, const float* __restrict__ bp1,
        const float* __restrict__ Wp2, const float* __restrict__ bp2,
        const float* __restrict__ Wv1, const float* __restrict__ bv1,
        const float* __restrict__ Wv2, const float* __restrict__ bv2,
        float* __restrict__ out) {
    __shared__ float fr[16][128];
    __shared__ float hh[16][128];
    int tid = threadIdx.x;
    bool is_val = blockIdx.x >= 256;
    int r0 = (is_val ? blockIdx.x - 256 : blockIdx.x) * 16;
    const float* Wa = is_val ? Wv1 : Wp1;
    const float* ba = is_val ? bv1 : bp1;

    ((float4*)&fr[0][0])[tid] = ((const float4*)(feat + (size_t)r0 * HID))[tid];
    __syncthreads();
    int c = tid & 127, g = tid >> 7;
    float acc[4];
    float bb = ba[c];
#pragma unroll
    for (int r = 0; r < 4; r++) acc[r] = bb;
#pragma unroll 8
    for (int k = 0; k < HID; k++) {
        float w = Wa[k * HID + c];
#pragma unroll
        for (int r = 0; r < 4; r++) acc[r] += w * fr[g * 4 + r][k];
    }
#pragma unroll
    for (int r = 0; r < 4; r++) hh[g * 4 + r][c] = fmaxf(acc[r], 0.f);
    __syncthreads();

    int c2 = tid & 31, r = tid >> 5;
    if (!is_val) {
        float lacc = bp2[c2];
#pragma unroll 8
        for (int k = 0; k < HID; k++) lacc += hh[r][k] * Wp2[k * 32 + c2];
        float mx = lacc;
#pragma unroll
        for (int s = 16; s >= 1; s >>= 1) mx = fmaxf(mx, __shfl_xor(mx, s, 32));
        float e = __expf(lacc - mx);
        float sm = e;
#pragma unroll
        for (int s = 16; s >= 1; s >>= 1) sm += __shfl_xor(sm, s, 32);
        out[(size_t)(r0 + r) * 32 + c2] = e / sm;
    } else {
        float p = 0.f;
#pragma unroll
        for (int j = 0; j < 4; j++) p += hh[r][c2 + j * 32] * Wv2[c2 + j * 32];
#pragma unroll
        for (int s = 16; s >= 1; s >>= 1) p += __shfl_xor(p, s, 32);
        if (c2 == 0) out[131072 + r0 + r] = p + bv2[0];
    }
}

extern "C" void kernel_launch(void* const* d_in, const int* in_sizes, int n_in,
                              void* d_out, int out_size, void* d_ws, size_t ws_size,
                              hipStream_t stream) {
    const float* state = (const float*)d_in[0];
    const int*   adj   = (const int*)d_in[1];
    const float* W1  = (const float*)d_in[2];
    const float* b1  = (const float*)d_in[3];
    const float* W2  = (const float*)d_in[4];
    const float* b2  = (const float*)d_in[5];
    const float* Wg  = (const float*)d_in[6];
    const float* ag  = (const float*)d_in[7];
    const float* Wp1 = (const float*)d_in[8];
    const float* bp1 = (const float*)d_in[9];
    const float* Wp2 = (const float*)d_in[10];
    const float* bp2 = (const float*)d_in[11];
    const float* Wv1 = (const float*)d_in[12];
    const float* bv1 = (const float*)d_in[13];
    const float* Wv2 = (const float*)d_in[14];
    const float* bv2 = (const float*)d_in[15];
    float* out = (float*)d_out;
    float* ws = (float*)d_ws;

    unsigned short* hTf = (unsigned short*)ws;          // 524288 bf16
    float* s1b  = ws + 262144;
    float* s2b  = ws + 278528;
    float* E2   = ws + 294912;
    float* E2s  = ws + 311296;
    float* cpos = ws + 327680;
    float* cneg = ws + 344064;
    float* thr  = ws + 360448;
    unsigned int* abit = (unsigned int*)(ws + 376832);  // 2 MB
    float* feat = ws + 376832;                          // overlaps abit (dead by then)
    __half* pout = (__half*)(ws + 901120);              // 16.8M fp16
    float* pden = ws + 9289728;

    hipLaunchKernelGGL(k_prep_pack, dim3(512 + NN), dim3(256), 0, stream,
                       state, W1, b1, W2, b2, Wg, ag, adj, hTf, s1b, s2b, abit);
    hipLaunchKernelGGL(k_headprep, dim3(HEADS), dim3(256), 0, stream,
                       s1b, s2b, E2, E2s, cpos, cneg, thr);
    hipLaunchKernelGGL(k_attn, dim3(64 * NSPLIT), dim3(256), 0, stream,
                       abit, hTf, s2b, E2, E2s, cpos, cneg, thr, pout, pden);
    hipLaunchKernelGGL(k_reduce, dim3((HEADS * NN * FF) / 256), dim3(256), 0, stream,
                       pout, pden, feat);
    hipLaunchKernelGGL(k_polval, dim3(512), dim3(512), 0, stream,
                       feat, Wp1, bp1, Wp2, bp2, Wv1, bv1, Wv2, bv2, out);
}